// Round 17
// baseline (185.006 us; speedup 1.0000x reference)
//
#include <hip/hip_runtime.h>
#include <hip/hip_cooperative_groups.h>

namespace cg = cooperative_groups;

// Output layout (flat f32, reference return order):
//   out0 : (1024,50,3)  @ 0       (153600)
//   steps: (1024,3,49)  @ 153600  (150528)  all 0.01
//   eps  : (1024,3)     @ 304128  (3072)    analytic 0
//   var  : (1024,50,3)  @ 307200  (153600)
//   xi   : (1,10,3)     @ 460800  (30)
#define OUT0_OFF  0
#define STEPS_OFF 153600
#define EPS_OFF   304128
#define VAR_OFF   307200
#define XI_OFF    460800

typedef short bf16x8 __attribute__((ext_vector_type(8)));
typedef float f32x4  __attribute__((ext_vector_type(4)));
typedef unsigned short u16x8 __attribute__((ext_vector_type(8)));

__device__ __forceinline__ unsigned short f2bf(float x) {   // RNE f32->bf16
    union { float f; unsigned u; } c; c.f = x;
    return (unsigned short)((c.u + 0x7FFFu + ((c.u >> 16) & 1u)) >> 16);
}
__device__ __forceinline__ float bf2f(unsigned short h) {
    union { float f; unsigned u; } c; c.u = ((unsigned)h) << 16;
    return c.f;
}

struct Params {
    const float *net_iv, *param_in, *pW1, *pb1, *pW2, *pb2, *pW3, *pb3;
    const float *nW1, *nb1, *nW2, *nb2, *nW3, *nb3, *mask;
    unsigned short *H1h, *H1l, *W2Th, *W2Tl, *B3Th, *B3Tl, *H2h, *H2l;
    float *pvec, *h1p;
    float *out0, *steps, *eps, *varp, *xi;
    int lo, hi;
};

// ---------------- transpose+split units (64x64 tile, 256 thr) -----------------
__device__ void transp2_unit(const Params& p, char* sm, int u) {
    float* Ts = (float*)sm;                        // [64][65]
    const int t = threadIdx.x;
    const int n0 = (u & 15) * 64, k0 = (u >> 4) * 64;
    const int g = t >> 6, l = t & 63;
    #pragma unroll
    for (int i = 0; i < 16; ++i) {
        const int kl = g * 16 + i;
        Ts[kl * 65 + l] = p.nW2[(k0 + kl) * 1024 + n0 + l];
    }
    __syncthreads();
    #pragma unroll
    for (int i = 0; i < 16; ++i) {
        const int nl = g * 16 + i;
        const float x = Ts[l * 65 + nl];
        const unsigned short h = f2bf(x);
        p.W2Th[(long)(n0 + nl) * 1024 + k0 + l] = h;
        p.W2Tl[(long)(n0 + nl) * 1024 + k0 + l] = f2bf(x - bf2f(h));
    }
}

__device__ void transp3_unit(const Params& p, char* sm, int u) {
    float* Ts = (float*)sm;
    const int t = threadIdx.x;
    const int n0 = (u % 3) * 64, k0 = (u / 3) * 64;
    const int g = t >> 6, l = t & 63;
    #pragma unroll
    for (int i = 0; i < 16; ++i) {
        const int kl = g * 16 + i;
        const int n = n0 + l;
        Ts[kl * 65 + l] = (n < 150) ? p.nW3[(k0 + kl) * 150 + n] : 0.f;
    }
    __syncthreads();
    #pragma unroll
    for (int i = 0; i < 16; ++i) {
        const int nl = g * 16 + i;
        const float x = Ts[l * 65 + nl];
        const unsigned short h = f2bf(x);
        p.B3Th[(long)(n0 + nl) * 1024 + k0 + l] = h;
        p.B3Tl[(long)(n0 + nl) * 1024 + k0 + l] = f2bf(x - bf2f(h));
    }
}

// ---------------- GEMM1 unit: 32x64 f32 tile, 256 thr, whole K in LDS ---------
// Per-element k-order identical to prior rounds -> H1 bits unchanged.
__device__ void gemm1_unit(const Params& p, char* sm, int u) {
    float* As = (float*)sm;                        // [150][36] transposed
    float* Bs = (float*)(sm + 21600);              // [150][64]
    const int t = threadIdx.x;
    const int row0 = (u >> 4) * 32;
    const int col0 = (u & 15) * 64;

    for (int i = t; i < 4800; i += 256) {
        const int r = i / 150;
        const int k = i - r * 150;
        As[k * 36 + r] = p.net_iv[row0 * 150 + i];
    }
    {
        const int c4 = (t & 15) * 4;
        for (int k = t >> 4; k < 150; k += 16)
            *(float4*)&Bs[k * 64 + c4] =
                *(const float4*)(p.nW1 + k * 1024 + col0 + c4);
    }
    __syncthreads();

    const int tx4 = (t & 15) * 4;
    const int ty2 = (t >> 4) * 2;
    float acc[2][4] = {};
    float2 aA = *(const float2*)&As[0 * 36 + ty2];
    float4 bA = *(const float4*)&Bs[0 * 64 + tx4];
    float2 aB = *(const float2*)&As[1 * 36 + ty2];
    float4 bB = *(const float4*)&Bs[1 * 64 + tx4];
    #pragma unroll 5
    for (int k = 0; k < 150; k += 2) {
        float2 aN0 = {}; float4 bN0 = {};
        float2 aN1 = {}; float4 bN1 = {};
        if (k + 2 < 150) {
            aN0 = *(const float2*)&As[(k + 2) * 36 + ty2];
            bN0 = *(const float4*)&Bs[(k + 2) * 64 + tx4];
        }
        if (k + 3 < 150) {
            aN1 = *(const float2*)&As[(k + 3) * 36 + ty2];
            bN1 = *(const float4*)&Bs[(k + 3) * 64 + tx4];
        }
        {
            const float a_[2] = {aA.x, aA.y};
            const float b_[4] = {bA.x, bA.y, bA.z, bA.w};
            #pragma unroll
            for (int i = 0; i < 2; ++i)
                #pragma unroll
                for (int j = 0; j < 4; ++j)
                    acc[i][j] = fmaf(a_[i], b_[j], acc[i][j]);
        }
        {
            const float a_[2] = {aB.x, aB.y};
            const float b_[4] = {bB.x, bB.y, bB.z, bB.w};
            #pragma unroll
            for (int i = 0; i < 2; ++i)
                #pragma unroll
                for (int j = 0; j < 4; ++j)
                    acc[i][j] = fmaf(a_[i], b_[j], acc[i][j]);
        }
        aA = aN0; bA = bN0; aB = aN1; bB = bN1;
    }
    #pragma unroll
    for (int i = 0; i < 2; ++i) {
        const int r = row0 + ty2 + i;
        #pragma unroll
        for (int j = 0; j < 4; ++j) {
            const int c = col0 + tx4 + j;
            const float v = fmaxf(acc[i][j] + p.nb1[c], 0.f);
            const unsigned short h = f2bf(v);
            p.H1h[r * 1024 + c] = h;
            p.H1l[r * 1024 + c] = f2bf(v - bf2f(h));
        }
    }
}

// ---------------- small matvec units ------------------------------------------
__device__ void mv1_unit(const Params& p) {
    const int t = threadIdx.x;
    #pragma unroll
    for (int jb = 0; jb < 4; ++jb) {
        const int j = jb * 256 + t;
        float a = 0.f;
        for (int k = 0; k < 64; ++k)
            a = fmaf(p.param_in[k], p.pW1[k * 1024 + j], a);
        p.h1p[j] = fmaxf(a + p.pb1[j], 0.f);
    }
}

__device__ void mv2_unit(const Params& p, char* sm, int idx) {
    float* red = (float*)sm;                       // 256 floats
    const int t = threadIdx.x;
    const int jj = t & 15, kg = t >> 4;
    const int j = idx * 16 + jj;
    float acc = 0.f;
    const int k0 = kg * 64;
    for (int k = k0; k < k0 + 64; ++k)
        acc = fmaf(p.h1p[k], p.pW2[k * 1024 + j], acc);
    red[kg * 16 + jj] = acc;
    __syncthreads();
    if (kg == 0) {
        float s = 0.f;
        #pragma unroll
        for (int g = 0; g < 16; ++g) s += red[g * 16 + jj];
        p.pvec[j] = s;
    }
    __syncthreads();
}

__device__ void mv3_unit(const Params& p, char* sm, int idx) {
    float* red = (float*)sm;                       // 4 floats
    const int t = threadIdx.x;
    const int j = idx * 2 + (t >> 7);
    const int lane = t & 127;
    float acc = 0.f;
    for (int k = lane; k < 1024; k += 128) {
        float h = fmaxf(p.pvec[k] + p.pb2[k], 0.f);
        acc = fmaf(h, p.pW3[k * 30 + j], acc);
    }
    #pragma unroll
    for (int off = 32; off > 0; off >>= 1) acc += __shfl_down(acc, off, 64);
    if ((t & 63) == 0) red[t >> 6] = acc;
    __syncthreads();
    if ((t & 127) == 0)
        p.xi[j] = (red[t >> 6] + red[(t >> 6) + 1] + p.pb3[j]) * p.mask[j];
    __syncthreads();
}

// ---------------- split-bf16 MFMA GEMM core: 64x64 tile, full K ---------------
// D = Ah*Bh + (Ah*Bl + Al*Bh), separate accH/accL chains. 4 waves x 32x32.
// LDS [buf][mat 4][kg*528 + row*8] (R12-proven). Reg-staged, 2-deep prefetch.
__device__ void gemm_core(const unsigned short* __restrict__ Ah,
                          const unsigned short* __restrict__ Al,
                          const unsigned short* __restrict__ Bh,
                          const unsigned short* __restrict__ Bl,
                          int m0, int n0, char* sm,
                          f32x4 (&accH)[2][2], f32x4 (&accL)[2][2])
{
    unsigned short* L = (unsigned short*)sm;       // [2][4][2112]
    const int t = threadIdx.x;
    const int K = 1024, nk = 32;

    const int smat = t >> 6, sl = t & 63;
    const unsigned short* src = (smat == 0) ? Ah : (smat == 1) ? Al
                              : (smat == 2) ? Bh : Bl;
    const int srow0 = (smat < 2) ? m0 : n0;

    u16x8 gva[4], gvb[4];                          // two named sets (rule #20)
    auto load = [&](u16x8 (&g)[4], int kt) {
        const long kb = (long)kt * 32;
        #pragma unroll
        for (int c = 0; c < 4; ++c) {
            const int f = c * 64 + sl;
            const int row = f >> 2, kq = f & 3;
            g[c] = *(const u16x8*)(src + (long)(srow0 + row) * K + kb + kq * 8);
        }
    };
    auto store = [&](int buf, const u16x8 (&g)[4]) {
        #pragma unroll
        for (int c = 0; c < 4; ++c) {
            const int f = c * 64 + sl;
            const int row = f >> 2, kq = f & 3;
            *(u16x8*)(L + (buf * 4 + smat) * 2112 + kq * 528 + row * 8) = g[c];
        }
    };

    const int wv = t >> 6;
    const int r0 = (wv >> 1) * 32, c0 = (wv & 1) * 32;
    const int lane = t & 63, lr = lane & 15, kq = lane >> 4;

    auto comp = [&](int cur) {
        const short* lb = (const short*)(L + cur * 4 * 2112);
        bf16x8 fah[2], fal[2], fbh[2], fbl[2];
        #pragma unroll
        for (int rt = 0; rt < 2; ++rt) {
            const int o = kq * 528 + (r0 + rt * 16 + lr) * 8;
            fah[rt] = *(const bf16x8*)(lb + o);
            fal[rt] = *(const bf16x8*)(lb + 2112 + o);
        }
        #pragma unroll
        for (int ct = 0; ct < 2; ++ct) {
            const int o = kq * 528 + (c0 + ct * 16 + lr) * 8;
            fbh[ct] = *(const bf16x8*)(lb + 4224 + o);
            fbl[ct] = *(const bf16x8*)(lb + 6336 + o);
        }
        #pragma unroll
        for (int rt = 0; rt < 2; ++rt)
            #pragma unroll
            for (int ct = 0; ct < 2; ++ct) {
                accH[rt][ct] = __builtin_amdgcn_mfma_f32_16x16x32_bf16(
                                   fah[rt], fbh[ct], accH[rt][ct], 0, 0, 0);
                accL[rt][ct] = __builtin_amdgcn_mfma_f32_16x16x32_bf16(
                                   fah[rt], fbl[ct], accL[rt][ct], 0, 0, 0);
                accL[rt][ct] = __builtin_amdgcn_mfma_f32_16x16x32_bf16(
                                   fal[rt], fbh[ct], accL[rt][ct], 0, 0, 0);
            }
    };

    load(gva, 0);
    store(0, gva);
    load(gvb, 1);
    __syncthreads();
    for (int kt = 0; kt < nk; kt += 2) {
        if (kt + 2 < nk) load(gva, kt + 2);
        store(1, gvb);
        comp(0);
        __syncthreads();
        if (kt + 3 < nk) load(gvb, kt + 3);
        if (kt + 2 < nk) store(0, gva);
        comp(1);
        __syncthreads();
    }
}

// gemm2 unit: full-K H2 tile + fused bias+relu+hi/lo split (R11-proven epilogue)
__device__ void gemm2_unit(const Params& p, char* sm, int u) {
    const int n0 = (u & 15) * 64, m0 = (u >> 4) * 64;
    f32x4 accH[2][2] = {};
    f32x4 accL[2][2] = {};
    gemm_core(p.H1h, p.H1l, p.W2Th, p.W2Tl, m0, n0, sm, accH, accL);
    const int t = threadIdx.x;
    const int wv = t >> 6;
    const int r0 = (wv >> 1) * 32, c0 = (wv & 1) * 32;
    const int lane = t & 63, lr = lane & 15, kq = lane >> 4;
    #pragma unroll
    for (int rt = 0; rt < 2; ++rt)
        #pragma unroll
        for (int ct = 0; ct < 2; ++ct) {
            const int col = n0 + c0 + ct * 16 + lr;
            const float bv = p.nb2[col];
            #pragma unroll
            for (int j = 0; j < 4; ++j) {
                const long o = (long)(m0 + r0 + rt * 16 + kq * 4 + j) * 1024 + col;
                const float v = fmaxf(accH[rt][ct][j] + accL[rt][ct][j] + bv, 0.f);
                const unsigned short h = f2bf(v);
                p.H2h[o] = h;
                p.H2l[o] = f2bf(v - bf2f(h));
            }
        }
}

// gemm3 unit: full-K var tile, writes varp directly (+nb3), cols<150 guarded
__device__ void gemm3_unit(const Params& p, char* sm, int u) {
    const int n0 = (u % 3) * 64, m0 = (u / 3) * 64;
    f32x4 accH[2][2] = {};
    f32x4 accL[2][2] = {};
    gemm_core(p.H2h, p.H2l, p.B3Th, p.B3Tl, m0, n0, sm, accH, accL);
    const int t = threadIdx.x;
    const int wv = t >> 6;
    const int r0 = (wv >> 1) * 32, c0 = (wv & 1) * 32;
    const int lane = t & 63, lr = lane & 15, kq = lane >> 4;
    #pragma unroll
    for (int rt = 0; rt < 2; ++rt)
        #pragma unroll
        for (int ct = 0; ct < 2; ++ct) {
            const int col = n0 + c0 + ct * 16 + lr;
            if (col < 150) {
                const float bv = p.nb3[col];
                #pragma unroll
                for (int j = 0; j < 4; ++j) {
                    const long r = m0 + r0 + rt * 16 + kq * 4 + j;
                    p.varp[r * 150 + col] =
                        accH[rt][ct][j] + accL[rt][ct][j] + bv;
                }
            }
        }
}

// ode unit: basis -> rhs -> trapezoid + fills, 4 batches per block
__device__ void ode_unit(const Params& p, char* sm, int b0) {
    float* s_var = (float*)sm;                     // [4][152]
    float* s_xi  = (float*)(sm + 2432);            // [30]
    float* s_rhs = (float*)(sm + 2560);            // [4][50][3]
    const int t  = threadIdx.x;
    const int bl = t >> 6;
    const int b  = b0 * 4 + bl;
    const int lt = t & 63;
    if (t < 30) s_xi[t] = p.xi[t];
    for (int i = lt; i < 150; i += 64)
        s_var[bl * 152 + i] = p.varp[b * 150 + i];
    __syncthreads();
    if (lt < 50) {
        const float v0 = s_var[bl * 152 + lt * 3 + 0];
        const float v1 = s_var[bl * 152 + lt * 3 + 1];
        const float v2 = s_var[bl * 152 + lt * 3 + 2];
        const float bas[10] = {1.f, v0, v1, v2,
                               v0 * v0, v0 * v1, v0 * v2,
                               v1 * v1, v1 * v2, v2 * v2};
        #pragma unroll
        for (int d = 0; d < 3; ++d) {
            float r = 0.f;
            #pragma unroll
            for (int k = 0; k < 10; ++k) r = fmaf(bas[k], s_xi[k * 3 + d], r);
            s_rhs[(bl * 50 + lt) * 3 + d] = r;
        }
    }
    __syncthreads();
    if (lt < 3) {
        float x = s_var[bl * 152 + lt];            // iv = var[b,0,lt]
        p.out0[b * 150 + lt] = x;
        for (int n = 1; n < 50; ++n) {
            x = fmaf(0.005f, s_rhs[(bl * 50 + n - 1) * 3 + lt] +
                             s_rhs[(bl * 50 + n) * 3 + lt], x);
            p.out0[b * 150 + n * 3 + lt] = x;
        }
        p.eps[b * 3 + lt] = 0.f;
    }
    for (int i = lt; i < 147; i += 64) p.steps[b * 147 + i] = 0.01f;
}

// ---------------- mega kernel: 4 stages, grid.sync between --------------------
__global__ __launch_bounds__(256, 1)
void mega_kernel(Params p)
{
    __shared__ __align__(16) char sm[61440];       // 60 KB arena
    cg::grid_group grid = cg::this_grid();
    const bool multi = (p.lo != p.hi);

    if (p.lo <= 0 && 0 <= p.hi) {                  // A: transposes + GEMM1 + mv1
        for (int u = blockIdx.x; u < 817; u += gridDim.x) {
            __syncthreads();
            if (u < 256)       transp2_unit(p, sm, u);
            else if (u < 304)  transp3_unit(p, sm, u - 256);
            else if (u < 816)  gemm1_unit(p, sm, u - 304);
            else               mv1_unit(p);
        }
    }
    if (multi) grid.sync();
    if (p.lo <= 1 && 1 <= p.hi) {                  // B: GEMM2 + mv2
        for (int u = blockIdx.x; u < 320; u += gridDim.x) {
            __syncthreads();
            if (u < 256) gemm2_unit(p, sm, u);
            else         mv2_unit(p, sm, u - 256);
        }
    }
    if (multi) grid.sync();
    if (p.lo <= 2 && 2 <= p.hi) {                  // C: GEMM3 + mv3
        for (int u = blockIdx.x; u < 63; u += gridDim.x) {
            __syncthreads();
            if (u < 48) gemm3_unit(p, sm, u);
            else        mv3_unit(p, sm, u - 48);
        }
    }
    if (multi) grid.sync();
    if (p.lo <= 3 && 3 <= p.hi) {                  // D: ode
        __syncthreads();
        ode_unit(p, sm, blockIdx.x);
    }
}

extern "C" void kernel_launch(void* const* d_in, const int* in_sizes, int n_in,
                              void* d_out, int out_size, void* d_ws, size_t ws_size,
                              hipStream_t stream)
{
    Params p;
    p.net_iv   = (const float*)d_in[0];
    p.param_in = (const float*)d_in[1];
    p.pW1 = (const float*)d_in[2];
    p.pb1 = (const float*)d_in[3];
    p.pW2 = (const float*)d_in[4];
    p.pb2 = (const float*)d_in[5];
    p.pW3 = (const float*)d_in[6];
    p.pb3 = (const float*)d_in[7];
    p.nW1 = (const float*)d_in[8];
    p.nb1 = (const float*)d_in[9];
    p.nW2 = (const float*)d_in[10];
    p.nb2 = (const float*)d_in[11];
    p.nW3 = (const float*)d_in[12];
    p.nb3 = (const float*)d_in[13];
    p.mask= (const float*)d_in[14];

    float* out = (float*)d_out;
    p.out0  = out + OUT0_OFF;
    p.steps = out + STEPS_OFF;
    p.eps   = out + EPS_OFF;
    p.varp  = out + VAR_OFF;
    p.xi    = out + XI_OFF;

    // ws: bf16 buffers then f32 vectors (~14 MB of 256 MiB)
    unsigned short* w = (unsigned short*)d_ws;
    p.H1h  = w;               w += 1048576;
    p.H1l  = w;               w += 1048576;
    p.W2Th = w;               w += 1048576;
    p.W2Tl = w;               w += 1048576;
    p.H2h  = w;               w += 1048576;
    p.H2l  = w;               w += 1048576;
    p.B3Th = w;               w += 196608;
    p.B3Tl = w;               w += 196608;
    p.pvec = (float*)w;
    p.h1p  = p.pvec + 1024;

    dim3 grid(256), block(256);
    p.lo = 0; p.hi = 3;
    void* args[] = { &p };
    hipError_t e = hipLaunchCooperativeKernel((void*)mega_kernel, grid, block,
                                              args, 0, stream);
    if (e != hipSuccess) {
        // fallback: 4 sequential stage launches (no grid.sync executed)
        for (int s = 0; s < 4; ++s) {
            p.lo = p.hi = s;
            hipLaunchKernelGGL(mega_kernel, grid, block, 0, stream, p);
        }
    }
}

// Round 18
// 72.148 us; speedup vs baseline: 2.5643x; 2.5643x over previous
//
#include <hip/hip_runtime.h>

// Output layout (flat f32, reference return order):
//   out0 : (1024,50,3)  @ 0       (153600)
//   steps: (1024,3,49)  @ 153600  (150528)  all 0.01
//   eps  : (1024,3)     @ 304128  (3072)    analytic 0
//   var  : (1024,50,3)  @ 307200  (153600)
//   xi   : (1,10,3)     @ 460800  (30)
#define OUT0_OFF  0
#define STEPS_OFF 153600
#define EPS_OFF   304128
#define VAR_OFF   307200
#define XI_OFF    460800

typedef short bf16x8 __attribute__((ext_vector_type(8)));
typedef float f32x4  __attribute__((ext_vector_type(4)));
typedef unsigned short u16x8 __attribute__((ext_vector_type(8)));
typedef unsigned short u16x4 __attribute__((ext_vector_type(4)));

__device__ __forceinline__ unsigned short f2bf(float x) {   // RNE f32->bf16
    union { float f; unsigned u; } c; c.f = x;
    return (unsigned short)((c.u + 0x7FFFu + ((c.u >> 16) & 1u)) >> 16);
}
__device__ __forceinline__ float bf2f(unsigned short h) {
    union { float f; unsigned u; } c; c.u = ((unsigned)h) << 16;
    return c.f;
}

__device__ __forceinline__ void fma16v(const float4& av, const float4& bv,
                                       float acc[4][4]) {
    const float a_[4] = {av.x, av.y, av.z, av.w};
    const float b_[4] = {bv.x, bv.y, bv.z, bv.w};
    #pragma unroll
    for (int i = 0; i < 4; ++i)
        #pragma unroll
        for (int j = 0; j < 4; ++j)
            acc[i][j] = fmaf(a_[i], b_[j], acc[i][j]);
}

// ---------------- GEMM1 + mv1 piggyback ---------------------------------------
// H1 = relu(net_iv(1024x150) @ nW1 + nb1), emitted as bf16 hi/lo split pair.
__global__ __launch_bounds__(128)
void gemm1_k150(const float* __restrict__ A, const float* __restrict__ B,
                const float* __restrict__ bias,
                unsigned short* __restrict__ H1h, unsigned short* __restrict__ H1l,
                const float* __restrict__ px, const float* __restrict__ pW1,
                const float* __restrict__ pb1, float* __restrict__ h1p)
{
    __shared__ __align__(16) float As[150][36];   // transposed A, 21.6 KB
    __shared__ __align__(16) float Bs[150][64];   // 38.4 KB
    const int t = threadIdx.x;

    if (blockIdx.x == 16) {                       // mv1: 32 blocks x 32 j
        float* red = &As[0][0];
        const int jj = t & 31, kg = t >> 5;
        const int j = blockIdx.y * 32 + jj;
        float acc = 0.f;
        for (int k = kg * 16; k < kg * 16 + 16; ++k)
            acc = fmaf(px[k], pW1[k * 1024 + j], acc);
        red[kg * 32 + jj] = acc;
        __syncthreads();
        if (kg == 0) {
            float s = red[jj] + red[32 + jj] + red[64 + jj] + red[96 + jj];
            h1p[j] = fmaxf(s + pb1[j], 0.f);
        }
        return;
    }

    const int col0 = blockIdx.x * 64;
    const int row0 = blockIdx.y * 32;

    for (int i = t; i < 4800; i += 128) {
        const int r = i / 150;
        const int k = i - r * 150;
        As[k][r] = A[row0 * 150 + i];
    }
    {
        const int c4 = (t & 15) * 4;
        for (int k = t >> 4; k < 150; k += 8)
            *(float4*)&Bs[k][c4] = *(const float4*)(B + k * 1024 + col0 + c4);
    }
    __syncthreads();

    const int tx4 = (t & 15) * 4;
    const int ty4 = (t >> 4) * 4;
    float acc[4][4] = {};
    float4 aA = *(const float4*)&As[0][ty4], bA = *(const float4*)&Bs[0][tx4];
    float4 aB = *(const float4*)&As[1][ty4], bB = *(const float4*)&Bs[1][tx4];
    #pragma unroll 5
    for (int k = 0; k < 150; k += 2) {
        float4 aN0 = {}, bN0 = {}, aN1 = {}, bN1 = {};
        if (k + 2 < 150) {
            aN0 = *(const float4*)&As[k + 2][ty4];
            bN0 = *(const float4*)&Bs[k + 2][tx4];
        }
        if (k + 3 < 150) {
            aN1 = *(const float4*)&As[k + 3][ty4];
            bN1 = *(const float4*)&Bs[k + 3][tx4];
        }
        fma16v(aA, bA, acc);
        fma16v(aB, bB, acc);
        aA = aN0; bA = bN0; aB = aN1; bB = bN1;
    }
    #pragma unroll
    for (int i = 0; i < 4; ++i) {
        const int r = row0 + ty4 + i;
        #pragma unroll
        for (int j = 0; j < 4; ++j) {
            const int c = col0 + tx4 + j;
            const float v = fmaxf(acc[i][j] + bias[c], 0.f);
            const unsigned short h = f2bf(v);
            H1h[r * 1024 + c] = h;
            H1l[r * 1024 + c] = f2bf(v - bf2f(h));
        }
    }
}

// ------- merged transpose: bx<16 -> nW2 -> W2T hi/lo ; bx>=16 -> nW3 -> B3T ---
__global__ __launch_bounds__(256)
void transp_both(const float* __restrict__ w2,
                 unsigned short* __restrict__ t2h, unsigned short* __restrict__ t2l,
                 const float* __restrict__ w3,
                 unsigned short* __restrict__ t3h, unsigned short* __restrict__ t3l)
{
    __shared__ float Ts[64][65];
    const int t = threadIdx.x;
    const bool w3path = blockIdx.x >= 16;
    const int n0 = (w3path ? (blockIdx.x - 16) : blockIdx.x) * 64;
    const int k0 = blockIdx.y * 64;
    const int g = t >> 6;
    const int l = t & 63;
    #pragma unroll
    for (int i = 0; i < 16; ++i) {
        const int kl = g * 16 + i;
        if (w3path) {
            const int n = n0 + l;
            Ts[kl][l] = (n < 150) ? w3[(k0 + kl) * 150 + n] : 0.f;
        } else {
            Ts[kl][l] = w2[(k0 + kl) * 1024 + n0 + l];
        }
    }
    __syncthreads();
    unsigned short* th = w3path ? t3h : t2h;
    unsigned short* tl = w3path ? t3l : t2l;
    #pragma unroll
    for (int i = 0; i < 16; ++i) {
        const int nl = g * 16 + i;
        const float x = Ts[l][nl];
        const unsigned short h = f2bf(x);
        th[(long)(n0 + nl) * 1024 + k0 + l] = h;
        tl[(long)(n0 + nl) * 1024 + k0 + l] = f2bf(x - bf2f(h));
    }
}

// ---------------- gemm2_mfma: 64x64 tile, 4 waves x 32x32, split-K=2 ----------
// R12 kernel + XCD-tile swizzle (T1): each XCD owns a 4(by) x 8(bx) tile block
// -> per-XCD L2 working set 3 MB <= 4 MB; A/B panel reads become L2 hits.
// Grid (16,16,3): z<2 compute (kchunk 512, nk=16); z==2 -> mv2.
__global__ __launch_bounds__(256, 1)
void gemm2_mfma(const unsigned short* __restrict__ Ah, const unsigned short* __restrict__ Al,
                const unsigned short* __restrict__ Bh, const unsigned short* __restrict__ Bl,
                float* __restrict__ P2,
                const float* __restrict__ mx, const float* __restrict__ mW,
                float* __restrict__ my)
{
    __shared__ __align__(16) unsigned short L[2][4][2112];   // 33.8 KB
    const int t = threadIdx.x;

    if (blockIdx.z == 2) {                         // mv2: 64 blocks x 16 j
        const int idx = blockIdx.y * 16 + blockIdx.x;
        if (idx >= 64) return;
        float* red = (float*)&L[0][0][0];
        const int jj = t & 15, kg = t >> 4;
        const int j = idx * 16 + jj;
        float acc = 0.f;
        const int k0 = kg * 64;
        for (int k = k0; k < k0 + 64; ++k)
            acc = fmaf(mx[k], mW[k * 1024 + j], acc);
        red[kg * 16 + jj] = acc;
        __syncthreads();
        if (kg == 0) {
            float s = 0.f;
            #pragma unroll
            for (int g = 0; g < 16; ++g) s += red[g * 16 + jj];
            my[j] = s;
        }
        return;
    }

    // XCD-tile swizzle: xcd = x%8 (natural dispatch, gridDim.x=16 mult of 8).
    // Decode b=xcd>>1 (by-band), c=xcd&1 (bx-band), v=(x>>3)*16+y in-tile.
    const int x = blockIdx.x, y = blockIdx.y;
    const int xcd = x & 7;
    const int v   = ((x >> 3) << 4) + y;           // 0..31
    const int by  = (xcd >> 1) * 4 + (v & 3);      // 0..15
    const int bx  = (xcd & 1) * 8 + (v >> 2);      // 0..15
    const int m0 = by * 64;
    const int n0 = bx * 64;
    const int K = 1024, nk = 16;                   // kchunk 512
    const long kbase = (long)blockIdx.z * 512;

    const int sm = t >> 6;                         // wave stages one matrix
    const int sl = t & 63;
    const unsigned short* src = (sm == 0) ? Ah : (sm == 1) ? Al
                              : (sm == 2) ? Bh : Bl;
    const int srow0 = (sm < 2) ? m0 : n0;

    u16x8 gv[4];
    auto stage_load = [&](int kt) {                // T14: issue early
        const long kb = kbase + (long)kt * 32;
        #pragma unroll
        for (int c2 = 0; c2 < 4; ++c2) {
            const int flat = c2 * 64 + sl;
            const int row = flat >> 2, kg = flat & 3;
            gv[c2] = *(const u16x8*)(src + (long)(srow0 + row) * K + kb + kg * 8);
        }
    };
    auto stage_write = [&](int buf) {              // T14: write late
        #pragma unroll
        for (int c2 = 0; c2 < 4; ++c2) {
            const int flat = c2 * 64 + sl;
            const int row = flat >> 2, kg = flat & 3;
            *(u16x8*)&L[buf][sm][kg * 528 + row * 8] = gv[c2];
        }
    };

    const int wv = t >> 6;
    const int r0 = (wv >> 1) * 32, c0 = (wv & 1) * 32;
    const int lane = t & 63, lr = lane & 15, kg = lane >> 4;

    f32x4 accH[2][2] = {};
    f32x4 accL[2][2] = {};
    stage_load(0);
    stage_write(0);
    __syncthreads();
    for (int kt = 0; kt < nk; ++kt) {
        const int buf = kt & 1;
        if (kt + 1 < nk) stage_load(kt + 1);
        const short* lb = (const short*)&L[buf][0][0];
        bf16x8 fah[2], fal[2], fbh[2], fbl[2];
        #pragma unroll
        for (int rt = 0; rt < 2; ++rt) {
            const int o = kg * 528 + (r0 + rt * 16 + lr) * 8;
            fah[rt] = *(const bf16x8*)(lb + o);
            fal[rt] = *(const bf16x8*)(lb + 2112 + o);
        }
        #pragma unroll
        for (int ct = 0; ct < 2; ++ct) {
            const int o = kg * 528 + (c0 + ct * 16 + lr) * 8;
            fbh[ct] = *(const bf16x8*)(lb + 4224 + o);
            fbl[ct] = *(const bf16x8*)(lb + 6336 + o);
        }
        #pragma unroll
        for (int rt = 0; rt < 2; ++rt)
            #pragma unroll
            for (int ct = 0; ct < 2; ++ct) {
                accH[rt][ct] = __builtin_amdgcn_mfma_f32_16x16x32_bf16(
                                   fah[rt], fbh[ct], accH[rt][ct], 0, 0, 0);
                accL[rt][ct] = __builtin_amdgcn_mfma_f32_16x16x32_bf16(
                                   fah[rt], fbl[ct], accL[rt][ct], 0, 0, 0);
                accL[rt][ct] = __builtin_amdgcn_mfma_f32_16x16x32_bf16(
                                   fal[rt], fbh[ct], accL[rt][ct], 0, 0, 0);
            }
        if (kt + 1 < nk) stage_write(buf ^ 1);
        __syncthreads();
    }

    // C/D layout: row = (lane>>4)*4 + j, col = lane&15  [m89-verified]
    float* Cb = P2 + (long)blockIdx.z * 1048576;
    #pragma unroll
    for (int rt = 0; rt < 2; ++rt)
        #pragma unroll
        for (int ct = 0; ct < 2; ++ct)
            #pragma unroll
            for (int j = 0; j < 4; ++j)
                Cb[(long)(m0 + r0 + rt * 16 + kg * 4 + j) * 1024 +
                   (n0 + c0 + ct * 16 + lr)] = accH[rt][ct][j] + accL[rt][ct][j];
}

// ---------------- gemm3_mfma: A-stage fuses P2-reduce+bias+relu+split ---------
// R12 kernel + XCD co-location: grid (64,8); g decodes so the 4 blocks sharing
// a by (A-panel) have ids == same mod 8 -> same XCD -> A read once per XCD.
// bxi==3 -> mv3 piggyback. f32 partials to P3[sk], reduced in ode.
__global__ __launch_bounds__(256, 1)
void gemm3_mfma(const float* __restrict__ P2, const float* __restrict__ nb2,
                const unsigned short* __restrict__ Bh, const unsigned short* __restrict__ Bl,
                float* __restrict__ P3,
                const float* __restrict__ pvec, const float* __restrict__ pb2,
                const float* __restrict__ pW3, const float* __restrict__ pb3,
                const float* __restrict__ mask, float* __restrict__ xi)
{
    __shared__ __align__(16) unsigned short L[2][4][2112];
    const int t = threadIdx.x;

    const int g   = blockIdx.x;                    // 0..63
    const int sk  = blockIdx.y;                    // 0..7
    const int bxi = (g >> 3) & 3;                  // 0..3
    const int by  = (g & 7) + ((g >> 5) << 3);     // 0..15

    if (bxi == 3) {                                // mv3: 15 blocks x 2 j
        const int idx = by * 8 + sk;
        if (idx >= 15) return;
        const int j = idx * 2 + (t >> 7);
        const int lane = t & 127;
        float acc = 0.f;
        for (int k = lane; k < 1024; k += 128) {
            float h = fmaxf(pvec[k] + pb2[k], 0.f);
            acc = fmaf(h, pW3[k * 30 + j], acc);
        }
        #pragma unroll
        for (int off = 32; off > 0; off >>= 1) acc += __shfl_down(acc, off, 64);
        float* red = (float*)&L[0][0][0];
        if ((t & 63) == 0) red[t >> 6] = acc;
        __syncthreads();
        if ((t & 127) == 0)
            xi[j] = (red[t >> 6] + red[(t >> 6) + 1] + pb3[j]) * mask[j];
        return;
    }

    const int m0 = by * 64;
    const int n0 = bxi * 64;
    const int nk = 4;                              // kchunk 128
    const long kbase = (long)sk * 128;

    float4 ga[2][2];                               // [c][partial-sum parts]
    u16x8 gb[2];
    auto stage_load = [&](int kt) {
        const long kb = kbase + (long)kt * 32;
        #pragma unroll
        for (int c = 0; c < 2; ++c) {
            const int idx = c * 256 + t;           // 0..511
            const int row = idx >> 3, q = idx & 7; // 64 rows x 8 f32-quads
            const long o = (long)(m0 + row) * 1024 + kb + q * 4;
            float4 p = *(const float4*)(P2 + o);
            float4 s = *(const float4*)(P2 + 1048576 + o);
            float4 bv = *(const float4*)(nb2 + kb + q * 4);
            ga[c][0].x = p.x + s.x + bv.x; ga[c][0].y = p.y + s.y + bv.y;
            ga[c][0].z = p.z + s.z + bv.z; ga[c][0].w = p.w + s.w + bv.w;
            ga[c][1] = ga[c][0];                   // placeholder (unused slot)
        }
        {
            const int row = t >> 2, kg = t & 3;    // 64 rows x 4 kgroups
            const long o = (long)(n0 + row) * 1024 + kb + kg * 8;
            gb[0] = *(const u16x8*)(Bh + o);
            gb[1] = *(const u16x8*)(Bl + o);
        }
    };
    auto stage_write = [&](int buf) {
        #pragma unroll
        for (int c = 0; c < 2; ++c) {
            const int idx = c * 256 + t;
            const int row = idx >> 3, q = idx & 7;
            const float v[4] = {fmaxf(ga[c][0].x, 0.f), fmaxf(ga[c][0].y, 0.f),
                                fmaxf(ga[c][0].z, 0.f), fmaxf(ga[c][0].w, 0.f)};
            u16x4 hh, ll;
            hh.x = f2bf(v[0]); ll.x = f2bf(v[0] - bf2f(hh.x));
            hh.y = f2bf(v[1]); ll.y = f2bf(v[1] - bf2f(hh.y));
            hh.z = f2bf(v[2]); ll.z = f2bf(v[2] - bf2f(hh.z));
            hh.w = f2bf(v[3]); ll.w = f2bf(v[3] - bf2f(hh.w));
            const int kg = q >> 1, half = (q & 1) * 4;
            *(u16x4*)&L[buf][0][kg * 528 + row * 8 + half] = hh;
            *(u16x4*)&L[buf][1][kg * 528 + row * 8 + half] = ll;
        }
        {
            const int row = t >> 2, kg = t & 3;
            *(u16x8*)&L[buf][2][kg * 528 + row * 8] = gb[0];
            *(u16x8*)&L[buf][3][kg * 528 + row * 8] = gb[1];
        }
    };

    const int wv = t >> 6;
    const int r0 = (wv >> 1) * 32, c0 = (wv & 1) * 32;
    const int lane = t & 63, lr = lane & 15, kg = lane >> 4;

    f32x4 accH[2][2] = {};
    f32x4 accL[2][2] = {};
    stage_load(0);
    stage_write(0);
    __syncthreads();
    for (int kt = 0; kt < nk; ++kt) {
        const int buf = kt & 1;
        if (kt + 1 < nk) stage_load(kt + 1);
        const short* lb = (const short*)&L[buf][0][0];
        bf16x8 fah[2], fal[2], fbh[2], fbl[2];
        #pragma unroll
        for (int rt = 0; rt < 2; ++rt) {
            const int o = kg * 528 + (r0 + rt * 16 + lr) * 8;
            fah[rt] = *(const bf16x8*)(lb + o);
            fal[rt] = *(const bf16x8*)(lb + 2112 + o);
        }
        #pragma unroll
        for (int ct = 0; ct < 2; ++ct) {
            const int o = kg * 528 + (c0 + ct * 16 + lr) * 8;
            fbh[ct] = *(const bf16x8*)(lb + 4224 + o);
            fbl[ct] = *(const bf16x8*)(lb + 6336 + o);
        }
        #pragma unroll
        for (int rt = 0; rt < 2; ++rt)
            #pragma unroll
            for (int ct = 0; ct < 2; ++ct) {
                accH[rt][ct] = __builtin_amdgcn_mfma_f32_16x16x32_bf16(
                                   fah[rt], fbh[ct], accH[rt][ct], 0, 0, 0);
                accL[rt][ct] = __builtin_amdgcn_mfma_f32_16x16x32_bf16(
                                   fah[rt], fbl[ct], accL[rt][ct], 0, 0, 0);
                accL[rt][ct] = __builtin_amdgcn_mfma_f32_16x16x32_bf16(
                                   fal[rt], fbh[ct], accL[rt][ct], 0, 0, 0);
            }
        if (kt + 1 < nk) stage_write(buf ^ 1);
        __syncthreads();
    }

    float* Cb = P3 + (long)sk * 196608;
    #pragma unroll
    for (int rt = 0; rt < 2; ++rt)
        #pragma unroll
        for (int ct = 0; ct < 2; ++ct)
            #pragma unroll
            for (int j = 0; j < 4; ++j)
                Cb[(long)(m0 + r0 + rt * 16 + kg * 4 + j) * 192 +
                   (n0 + c0 + ct * 16 + lr)] = accH[rt][ct][j] + accL[rt][ct][j];
}

// ---------------- ode: GEMM3 8-way reduce + basis/rhs/trapezoid, 4 b/block ----
__global__ __launch_bounds__(256)
void ode_kernel(const float* __restrict__ P3, const float* __restrict__ nb3,
                const float* __restrict__ xi, float* __restrict__ varp,
                float* __restrict__ out0, float* __restrict__ steps,
                float* __restrict__ eps)
{
    const int t  = threadIdx.x;
    const int bl = t >> 6;
    const int b  = blockIdx.x * 4 + bl;
    const int lt = t & 63;
    __shared__ float s_var[4][152];
    __shared__ float s_xi[30];
    __shared__ float s_rhs[4][50][3];
    if (t < 30) s_xi[t] = xi[t];
    for (int i = lt; i < 150; i += 64) {
        float v = nb3[i];
        #pragma unroll
        for (int s = 0; s < 8; ++s) v += P3[s * 196608 + b * 192 + i];
        s_var[bl][i] = v;
        varp[b * 150 + i] = v;
    }
    __syncthreads();
    if (lt < 50) {
        const float v0 = s_var[bl][lt * 3 + 0];
        const float v1 = s_var[bl][lt * 3 + 1];
        const float v2 = s_var[bl][lt * 3 + 2];
        const float bas[10] = {1.f, v0, v1, v2,
                               v0 * v0, v0 * v1, v0 * v2,
                               v1 * v1, v1 * v2, v2 * v2};
        #pragma unroll
        for (int d = 0; d < 3; ++d) {
            float r = 0.f;
            #pragma unroll
            for (int k = 0; k < 10; ++k) r = fmaf(bas[k], s_xi[k * 3 + d], r);
            s_rhs[bl][lt][d] = r;
        }
    }
    __syncthreads();
    if (lt < 3) {
        float x = s_var[bl][lt];              // iv = var[b,0,lt]
        out0[b * 150 + lt] = x;
        for (int n = 1; n < 50; ++n) {
            x = fmaf(0.005f, s_rhs[bl][n - 1][lt] + s_rhs[bl][n][lt], x);
            out0[b * 150 + n * 3 + lt] = x;
        }
        eps[b * 3 + lt] = 0.f;
    }
    for (int i = lt; i < 147; i += 64) steps[b * 147 + i] = 0.01f;
}

extern "C" void kernel_launch(void* const* d_in, const int* in_sizes, int n_in,
                              void* d_out, int out_size, void* d_ws, size_t ws_size,
                              hipStream_t stream)
{
    const float* net_iv   = (const float*)d_in[0];
    const float* param_in = (const float*)d_in[1];
    const float* pW1 = (const float*)d_in[2];
    const float* pb1 = (const float*)d_in[3];
    const float* pW2 = (const float*)d_in[4];
    const float* pb2 = (const float*)d_in[5];
    const float* pW3 = (const float*)d_in[6];
    const float* pb3 = (const float*)d_in[7];
    const float* nW1 = (const float*)d_in[8];
    const float* nb1 = (const float*)d_in[9];
    const float* nW2 = (const float*)d_in[10];
    const float* nb2 = (const float*)d_in[11];
    const float* nW3 = (const float*)d_in[12];
    const float* nb3 = (const float*)d_in[13];
    const float* mask= (const float*)d_in[14];

    float* out = (float*)d_out;
    float* out0p  = out + OUT0_OFF;
    float* stepsp = out + STEPS_OFF;
    float* epsp   = out + EPS_OFF;
    float* varp   = out + VAR_OFF;
    float* xip    = out + XI_OFF;

    // ws layout: bf16 buffers then f32. ~24 MB of 256 MiB.
    unsigned short* H1h  = (unsigned short*)d_ws;     // 1024x1024 each
    unsigned short* H1l  = H1h + 1048576;
    unsigned short* W2Th = H1l + 1048576;             // [n][k]
    unsigned short* W2Tl = W2Th + 1048576;
    unsigned short* B3Th = W2Tl + 1048576;            // [192][1024]
    unsigned short* B3Tl = B3Th + 196608;
    float* P2   = (float*)(B3Tl + 196608);            // 2 x 1048576 f32
    float* P3   = P2 + 2097152;                       // 8 x 196608 f32
    float* pvec = P3 + 1572864;                       // 1024
    float* h1p  = pvec + 1024;                        // 1024

    // prep: merged transpose+split of nW2 (bx<16) and nW3 (bx>=16)
    hipLaunchKernelGGL(transp_both, dim3(19, 16), dim3(256), 0, stream,
                       nW2, W2Th, W2Tl, nW3, B3Th, B3Tl);

    // k1: GEMM1 -> H1 hi/lo (+ mv1 piggyback on bx==16)
    hipLaunchKernelGGL(gemm1_k150, dim3(17, 32), dim3(128), 0, stream,
                       net_iv, nW1, nb1, H1h, H1l, param_in, pW1, pb1, h1p);

    // k2: GEMM2 MFMA 64x64, split-K=2, XCD-tile swizzle (+ mv2 on z==2)
    hipLaunchKernelGGL(gemm2_mfma, dim3(16, 16, 3), dim3(256), 0, stream,
                       H1h, H1l, W2Th, W2Tl, P2, h1p, pW2, pvec);

    // k3: GEMM3 MFMA 64x64, split-K=8, XCD co-located A-panels; A-stage fuses
    //     P2-reduce + bias + relu + hi/lo split (+ mv3 on bxi==3)
    hipLaunchKernelGGL(gemm3_mfma, dim3(64, 8), dim3(256), 0, stream,
                       P2, nb2, B3Th, B3Tl, P3, pvec, pb2, pW3, pb3, mask, xip);

    // k4: ode (reduce 8 partials + basis/rhs/trapezoid + fills)
    hipLaunchKernelGGL(ode_kernel, dim3(256), dim3(256), 0, stream,
                       P3, nb3, xip, varp, out0p, stepsp, epsp);
}